// Round 1
// 6668.233 us; speedup vs baseline: 1.3823x; 1.3823x over previous
//
#include <hip/hip_runtime.h>
#include <hip/hip_bf16.h>

typedef __bf16 bf8_t __attribute__((ext_vector_type(8)));
typedef float  f4_t  __attribute__((ext_vector_type(4)));
typedef unsigned u32x4 __attribute__((ext_vector_type(4)));

#define SENT 0xFFFFFFFFu

__device__ __forceinline__ unsigned short f2bf(float f) {
    unsigned u = __float_as_uint(f);
    unsigned r = (u + 0x7fffu + ((u >> 16) & 1u)) >> 16;   // RNE
    return (unsigned short)r;
}
__device__ __forceinline__ float bflo(unsigned u) { return __uint_as_float(u << 16); }
__device__ __forceinline__ float bfhi(unsigned u) { return __uint_as_float(u & 0xffff0000u); }
__device__ __forceinline__ float sigm(float x) {
    return __builtin_amdgcn_rcpf(1.f + __expf(-x));
}
__device__ __forceinline__ float tanh_fast(float x) {
    // 2*sigmoid(2x)-1; saturates correctly at both ends (no inf/inf)
    return 2.f * __builtin_amdgcn_rcpf(1.f + __expf(-2.f * x)) - 1.f;
}

// one 16B load that bypasses L1+L2 (reads from the agent-coherent point)
__device__ __forceinline__ u32x4 ld_coherent_x4(const unsigned* p) {
    u32x4 r;
    asm volatile("global_load_dwordx4 %0, %1, off sc0 sc1\n\t"
                 "s_waitcnt vmcnt(0)"
                 : "=v"(r) : "v"(p) : "memory");
    return r;
}

// ---------------- fill hs with sentinel ----------------
__global__ __launch_bounds__(256) void fill_sent(unsigned* __restrict__ hs) {
    uint4* p = (uint4*)(hs + (size_t)blockIdx.x * 1024);
    p[threadIdx.x] = make_uint4(SENT, SENT, SENT, SENT);
}

// ---------------- embedding gather ----------------
__global__ __launch_bounds__(256) void gather_emb(const int* __restrict__ sent,
                                                  const float* __restrict__ wte,
                                                  float* __restrict__ emb) {
    int srow = blockIdx.x;
    int v = sent[srow];
    const float4* src = (const float4*)(wte + (size_t)v * 1024);
    float4* dst = (float4*)(emb + (size_t)srow * 1024);
    dst[threadIdx.x] = src[threadIdx.x];
}

// ---------------- bf16 MFMA GEMM: C[M,N] = A[M,K] * B[N,K]^T + bias ----------------
__global__ __launch_bounds__(256) void gemm_bt(const float* __restrict__ A,
                                               const float* __restrict__ B,
                                               const float* __restrict__ bias0,
                                               const float* __restrict__ bias1,
                                               float* __restrict__ C,
                                               int M, int N, int K) {
    __shared__ unsigned short As[128][40];   // pitch 40 (+8 pad)
    __shared__ unsigned short Bs[128][40];
    const int tid  = threadIdx.x;
    const int lane = tid & 63;
    const int wave = tid >> 6;
    const int wm = wave >> 1, wn = wave & 1;
    const int m0 = blockIdx.x * 128, n0 = blockIdx.y * 128;
    const int lr = tid >> 3;            // staging row 0..31
    const int lc = tid & 7;             // staging float4 col 0..7
    const int frow = lane & 15;         // fragment row
    const int fk = (lane >> 4) << 3;    // fragment k offset (0,8,16,24)

    f4_t acc[4][4];
#pragma unroll
    for (int i = 0; i < 4; i++)
#pragma unroll
        for (int j = 0; j < 4; j++)
            acc[i][j] = f4_t{0.f, 0.f, 0.f, 0.f};

    for (int k0 = 0; k0 < K; k0 += 32) {
#pragma unroll
        for (int i = 0; i < 4; i++) {
            int row = lr + i * 32;
            float4 av = *(const float4*)(A + (size_t)(m0 + row) * K + k0 + lc * 4);
            unsigned lo = (unsigned)f2bf(av.x) | ((unsigned)f2bf(av.y) << 16);
            unsigned hi = (unsigned)f2bf(av.z) | ((unsigned)f2bf(av.w) << 16);
            *(uint2*)&As[row][lc * 4] = make_uint2(lo, hi);
            int gr = n0 + row;
            float4 bv = make_float4(0.f, 0.f, 0.f, 0.f);
            if (gr < N) bv = *(const float4*)(B + (size_t)gr * K + k0 + lc * 4);
            lo = (unsigned)f2bf(bv.x) | ((unsigned)f2bf(bv.y) << 16);
            hi = (unsigned)f2bf(bv.z) | ((unsigned)f2bf(bv.w) << 16);
            *(uint2*)&Bs[row][lc * 4] = make_uint2(lo, hi);
        }
        __syncthreads();
        bf8_t af[4], bfr[4];
#pragma unroll
        for (int i = 0; i < 4; i++) {
            af[i]  = *(const bf8_t*)&As[wm * 64 + i * 16 + frow][fk];
            bfr[i] = *(const bf8_t*)&Bs[wn * 64 + i * 16 + frow][fk];
        }
#pragma unroll
        for (int i = 0; i < 4; i++)
#pragma unroll
            for (int j = 0; j < 4; j++)
                acc[i][j] = __builtin_amdgcn_mfma_f32_16x16x32_bf16(af[i], bfr[j], acc[i][j], 0, 0, 0);
        __syncthreads();
    }

    const int rbase = m0 + wm * 64 + ((lane >> 4) << 2);
#pragma unroll
    for (int j = 0; j < 4; j++) {
        int col = n0 + wn * 64 + j * 16 + (lane & 15);
        if (col < N) {
            float bsum = bias0[col] + (bias1 ? bias1[col] : 0.f);
#pragma unroll
            for (int i = 0; i < 4; i++) {
                int rb = rbase + i * 16;
#pragma unroll
                for (int g = 0; g < 4; g++)
                    C[(size_t)(rb + g) * N + col] = acc[i][j][g] + bsum;
            }
        }
    }
}

// ---------------- persistent LSTM scan ----------------
// 128 WGs x 256 threads. WG w owns h-outputs j in [w*8, w*8+8); holds 32 rows of
// W_hh (4 gates x 8 j) as bf16 in LDS in a conflict-free tiled layout.
// Sync through hs[] sentinel values; h acquired with ONE dwordx4 sc0/sc1 load per thread.
__global__ __launch_bounds__(256, 1) void lstm_scan(const float* __restrict__ Whh,
                                                    const float* __restrict__ xg,
                                                    unsigned* __restrict__ hs) {
    extern __shared__ char smem[];
    unsigned short* Wl = (unsigned short*)smem;        // tiled, 65536 B
    float* hl   = (float*)(smem + 65536);              // [1024] -> 69632
    float* gbuf = (float*)(smem + 69632);              // [32]   -> 69760

    const int tid = threadIdx.x;
    const int wg  = blockIdx.x;

    // Preload + convert W_hh rows for this WG into tiled layout:
    //   Wl[ushort idx = i*2048 + r*64 + s*8 + j] = bf16(Whh[R(r)][64*i + 8*s + j])
    // so the wave's b128 read at iter i is exactly base(i,w) + 16*lane (conflict-free).
    for (int i0 = tid * 8; i0 < 32 * 1024; i0 += 256 * 8) {
        int r = i0 >> 10, k0 = i0 & 1023;
        int R = ((r >> 3) << 10) + wg * 8 + (r & 7);
        const float* src = Whh + (size_t)R * 1024 + k0;
        float4 a = *(const float4*)src;
        float4 b = *(const float4*)(src + 4);
        uint4 w;
        w.x = (unsigned)f2bf(a.x) | ((unsigned)f2bf(a.y) << 16);
        w.y = (unsigned)f2bf(a.z) | ((unsigned)f2bf(a.w) << 16);
        w.z = (unsigned)f2bf(b.x) | ((unsigned)f2bf(b.y) << 16);
        w.w = (unsigned)f2bf(b.z) | ((unsigned)f2bf(b.w) << 16);
        int i = k0 >> 6, s = (k0 >> 3) & 7;
        *(uint4*)(Wl + i * 2048 + r * 64 + s * 8) = w;
    }
    __syncthreads();

    const int r = tid >> 3;           // row 0..31 (gate = r>>3, j = r&7)
    const int s = tid & 7;            // k-slice 0..7
    const int R32 = ((r >> 3) << 10) + wg * 8 + (r & 7);
    float creg = 0.f;                 // cell state lives in tail-thread registers

    for (int t = 0; t < 2048; t++) {
        // prefetch xg BEFORE the spin so its latency hides under the wait
        float xgv = 0.f;
        if (s == 0) xgv = xg[(size_t)t * 4096 + R32];
        asm volatile("" :: "v"(xgv));   // anchor the load issue point

        // acquire h_{t-1}: one 16B coherent load per thread (256*16B = full h)
        if (t == 0) {
            *(f4_t*)(hl + 4 * tid) = f4_t{0.f, 0.f, 0.f, 0.f};
        } else {
            const unsigned* src = hs + (size_t)(t - 1) * 1024 + 4 * tid;
            u32x4 u = ld_coherent_x4(src);
            while (u.x == SENT || u.y == SENT || u.z == SENT || u.w == SENT) {
                __builtin_amdgcn_s_sleep(1);
                u = ld_coherent_x4(src);
            }
            *(u32x4*)(hl + 4 * tid) = u;
        }
        __syncthreads();   // barrier A: hl complete

        // partial dot: row r, k in {s*8 + 64*i}, conflict-free Wl reads
        float acc = 0.f;
#pragma unroll
        for (int i = 0; i < 16; i++) {
            uint4 wv = *(const uint4*)(Wl + i * 2048 + r * 64 + s * 8);
            const float* hp = hl + i * 64 + s * 8;
            float4 h0 = *(const float4*)hp;
            float4 h1 = *(const float4*)(hp + 4);
            acc += bflo(wv.x) * h0.x + bfhi(wv.x) * h0.y
                 + bflo(wv.y) * h0.z + bfhi(wv.y) * h0.w
                 + bflo(wv.z) * h1.x + bfhi(wv.z) * h1.y
                 + bflo(wv.w) * h1.z + bfhi(wv.w) * h1.w;
        }
        acc += __shfl_down(acc, 4);
        acc += __shfl_down(acc, 2);
        acc += __shfl_down(acc, 1);
        if (s == 0) gbuf[r] = acc + xgv;
        __syncthreads();   // barrier B: gbuf complete, hl reads done

        if (tid < 8) {
            float gi = sigm(gbuf[tid]);
            float gf = sigm(gbuf[8 + tid]);
            float gg = tanh_fast(gbuf[16 + tid]);
            float go = sigm(gbuf[24 + tid]);
            creg = gf * creg + gi * gg;
            float h = go * tanh_fast(creg);
            __hip_atomic_store(hs + (size_t)t * 1024 + wg * 8 + tid, __float_as_uint(h),
                               __ATOMIC_RELAXED, __HIP_MEMORY_SCOPE_AGENT);
        }
        // no trailing barrier needed:
        //  - next-iter hl writes are ordered after this iter's hl reads by barrier B
        //  - next-iter gbuf writes are ordered after tail's gbuf reads by barrier A(t+1)
        //  - sentinel protocol orders hs loads against stores
    }
}

// ---------------- in-place log_softmax over rows of N ----------------
__global__ __launch_bounds__(256) void logsoftmax_rows(float* __restrict__ P, int N) {
    __shared__ float sm[4], sl[4], sfin;
    const int tid = threadIdx.x;
    float* p = P + (size_t)blockIdx.x * N;
    float m = -3.4e38f, l = 0.f;
    for (int i = tid; i < N; i += 256) {
        float x = p[i];
        float M = fmaxf(m, x);
        l = l * __expf(m - M) + __expf(x - M);
        m = M;
    }
    for (int off = 32; off; off >>= 1) {
        float m2 = __shfl_down(m, off);
        float l2 = __shfl_down(l, off);
        float M = fmaxf(m, m2);
        l = l * __expf(m - M) + l2 * __expf(m2 - M);
        m = M;
    }
    if ((tid & 63) == 0) { sm[tid >> 6] = m; sl[tid >> 6] = l; }
    __syncthreads();
    if (tid == 0) {
        m = sm[0]; l = sl[0];
        for (int w = 1; w < 4; w++) {
            float M = fmaxf(m, sm[w]);
            l = l * __expf(m - M) + sl[w] * __expf(sm[w] - M);
            m = M;
        }
        sfin = m + logf(l);
    }
    __syncthreads();
    float lse = sfin;
    for (int i = tid; i < N; i += 256) p[i] = p[i] - lse;
}

extern "C" void kernel_launch(void* const* d_in, const int* in_sizes, int n_in,
                              void* d_out, int out_size, void* d_ws, size_t ws_size,
                              hipStream_t stream) {
    const int*   sentence = (const int*)  d_in[0];
    const float* wte      = (const float*)d_in[1];
    const float* W_ih     = (const float*)d_in[2];
    const float* W_hh     = (const float*)d_in[3];
    const float* b_ih     = (const float*)d_in[4];
    const float* b_hh     = (const float*)d_in[5];
    const float* W_head   = (const float*)d_in[6];
    const float* b_head   = (const float*)d_in[7];
    float* out = (float*)d_out;

    char* ws = (char*)d_ws;
    float* xg  = (float*)ws;                          // 2048*4096*4 = 33,554,432
    float* emb = (float*)(ws + 33554432);             // 2048*1024*4 =  8,388,608
    float* hsf = (float*)(ws + 41943040);             // 2048*1024*4 =  8,388,608
    unsigned* hsu = (unsigned*)hsf;

    hipFuncSetAttribute(reinterpret_cast<const void*>(lstm_scan),
                        hipFuncAttributeMaxDynamicSharedMemorySize, 69760);

    fill_sent<<<2048, 256, 0, stream>>>(hsu);
    gather_emb<<<2048, 256, 0, stream>>>(sentence, wte, emb);

    dim3 g1(2048 / 128, 4096 / 128);   // (16, 32)
    gemm_bt<<<g1, 256, 0, stream>>>(emb, W_ih, b_ih, b_hh, xg, 2048, 4096, 1024);

    lstm_scan<<<128, 256, 69760, stream>>>(W_hh, xg, hsu);

    dim3 g2(2048 / 128, (50257 + 127) / 128);  // (16, 393)
    gemm_bt<<<g2, 256, 0, stream>>>(hsf, W_head, b_head, nullptr, out, 2048, 50257, 1024);

    logsoftmax_rows<<<2048, 256, 0, stream>>>(out, 50257);
}

// Round 3
// 4902.551 us; speedup vs baseline: 1.8802x; 1.3602x over previous
//
#include <hip/hip_runtime.h>
#include <hip/hip_bf16.h>

typedef __bf16 bf8_t __attribute__((ext_vector_type(8)));
typedef float  f4_t  __attribute__((ext_vector_type(4)));
typedef float  f2_t  __attribute__((ext_vector_type(2)));
typedef unsigned u32x2 __attribute__((ext_vector_type(2)));

#define SENT 0xFFFFFFFFu

__device__ __forceinline__ unsigned short f2bf(float f) {
    unsigned u = __float_as_uint(f);
    unsigned r = (u + 0x7fffu + ((u >> 16) & 1u)) >> 16;   // RNE
    return (unsigned short)r;
}
__device__ __forceinline__ float sigm(float x) {
    return __builtin_amdgcn_rcpf(1.f + __expf(-x));
}
__device__ __forceinline__ float tanh_fast(float x) {
    // 2*sigmoid(2x)-1; saturates correctly at both ends
    return 2.f * __builtin_amdgcn_rcpf(1.f + __expf(-2.f * x)) - 1.f;
}
__device__ __forceinline__ f2_t pkfma(f2_t a, f2_t b, f2_t c) {
    f2_t d;
    asm("v_pk_fma_f32 %0, %1, %2, %3" : "=v"(d) : "v"(a), "v"(b), "v"(c));
    return d;
}
__device__ __forceinline__ f2_t lo2(f4_t v) { return __builtin_shufflevector(v, v, 0, 1); }
__device__ __forceinline__ f2_t hi2(f4_t v) { return __builtin_shufflevector(v, v, 2, 3); }

// 8B load that bypasses L1+L2 (reads from the agent-coherent point)
__device__ __forceinline__ u32x2 ld_coherent_x2(const unsigned* p) {
    u32x2 r;
    asm volatile("global_load_dwordx2 %0, %1, off sc0 sc1\n\t"
                 "s_waitcnt vmcnt(0)"
                 : "=v"(r) : "v"(p) : "memory");
    return r;
}

// ---------------- fill hs with sentinel ----------------
__global__ __launch_bounds__(256) void fill_sent(unsigned* __restrict__ hs) {
    uint4* p = (uint4*)(hs + (size_t)blockIdx.x * 1024);
    p[threadIdx.x] = make_uint4(SENT, SENT, SENT, SENT);
}

// ---------------- embedding gather ----------------
__global__ __launch_bounds__(256) void gather_emb(const int* __restrict__ sent,
                                                  const float* __restrict__ wte,
                                                  float* __restrict__ emb) {
    int srow = blockIdx.x;
    int v = sent[srow];
    const float4* src = (const float4*)(wte + (size_t)v * 1024);
    float4* dst = (float4*)(emb + (size_t)srow * 1024);
    dst[threadIdx.x] = src[threadIdx.x];
}

// ---------------- bf16 MFMA GEMM: C[M,N] = A[M,K] * B[N,K]^T + bias ----------------
__global__ __launch_bounds__(256) void gemm_bt(const float* __restrict__ A,
                                               const float* __restrict__ B,
                                               const float* __restrict__ bias0,
                                               const float* __restrict__ bias1,
                                               float* __restrict__ C,
                                               int M, int N, int K) {
    __shared__ unsigned short As[128][40];   // pitch 40 (+8 pad)
    __shared__ unsigned short Bs[128][40];
    const int tid  = threadIdx.x;
    const int lane = tid & 63;
    const int wave = tid >> 6;
    const int wm = wave >> 1, wn = wave & 1;
    const int m0 = blockIdx.x * 128, n0 = blockIdx.y * 128;
    const int lr = tid >> 3;            // staging row 0..31
    const int lc = tid & 7;             // staging float4 col 0..7
    const int frow = lane & 15;         // fragment row
    const int fk = (lane >> 4) << 3;    // fragment k offset (0,8,16,24)

    f4_t acc[4][4];
#pragma unroll
    for (int i = 0; i < 4; i++)
#pragma unroll
        for (int j = 0; j < 4; j++)
            acc[i][j] = f4_t{0.f, 0.f, 0.f, 0.f};

    for (int k0 = 0; k0 < K; k0 += 32) {
#pragma unroll
        for (int i = 0; i < 4; i++) {
            int row = lr + i * 32;
            float4 av = *(const float4*)(A + (size_t)(m0 + row) * K + k0 + lc * 4);
            unsigned lo = (unsigned)f2bf(av.x) | ((unsigned)f2bf(av.y) << 16);
            unsigned hi = (unsigned)f2bf(av.z) | ((unsigned)f2bf(av.w) << 16);
            *(uint2*)&As[row][lc * 4] = make_uint2(lo, hi);
            int gr = n0 + row;
            float4 bv = make_float4(0.f, 0.f, 0.f, 0.f);
            if (gr < N) bv = *(const float4*)(B + (size_t)gr * K + k0 + lc * 4);
            lo = (unsigned)f2bf(bv.x) | ((unsigned)f2bf(bv.y) << 16);
            hi = (unsigned)f2bf(bv.z) | ((unsigned)f2bf(bv.w) << 16);
            *(uint2*)&Bs[row][lc * 4] = make_uint2(lo, hi);
        }
        __syncthreads();
        bf8_t af[4], bfr[4];
#pragma unroll
        for (int i = 0; i < 4; i++) {
            af[i]  = *(const bf8_t*)&As[wm * 64 + i * 16 + frow][fk];
            bfr[i] = *(const bf8_t*)&Bs[wn * 64 + i * 16 + frow][fk];
        }
#pragma unroll
        for (int i = 0; i < 4; i++)
#pragma unroll
            for (int j = 0; j < 4; j++)
                acc[i][j] = __builtin_amdgcn_mfma_f32_16x16x32_bf16(af[i], bfr[j], acc[i][j], 0, 0, 0);
        __syncthreads();
    }

    const int rbase = m0 + wm * 64 + ((lane >> 4) << 2);
#pragma unroll
    for (int j = 0; j < 4; j++) {
        int col = n0 + wn * 64 + j * 16 + (lane & 15);
        if (col < N) {
            float bsum = bias0[col] + (bias1 ? bias1[col] : 0.f);
#pragma unroll
            for (int i = 0; i < 4; i++) {
                int rb = rbase + i * 16;
#pragma unroll
                for (int g = 0; g < 4; g++)
                    C[(size_t)(rb + g) * N + col] = acc[i][j][g] + bsum;
            }
        }
    }
}

// ---------------- persistent LSTM scan ----------------
// 64 WGs x 512 threads. WG w owns h-outputs j in [w*16, w*16+16).
// W_hh rows live in REGISTERS (f32): each thread holds 2 gate-rows x 64-wide
// k-slice = 128 VGPRs; dot via v_pk_fma_f32. h broadcast through double-buffered
// LDS (one barrier per step). Row mapping puts all 4 gates of a given j in one
// wave, so the tail (reduce -> gates -> c,h) is fully in-wave: no gbuf, no 2nd
// barrier. Sync across WGs through hs[] sentinels (store agent-scope, poll sc0sc1).
__global__ __launch_bounds__(512, 1) void lstm_scan(const float* __restrict__ Whh,
                                                    const float* __restrict__ xg,
                                                    unsigned* __restrict__ hs) {
    // hl pitch 68 floats: bank = (68*s+4i)%32 = (4s+4i)%32 -> 2-way max (free)
    __shared__ float hl[2][1088];   // 16 rows x 68, double-buffered

    const int tid = threadIdx.x;
    const int wv  = tid >> 6;        // wave 0..7
    const int l   = tid & 63;        // lane
    const int s   = l & 15;          // k-slice 0..15 (64 elements each)
    const int q   = l >> 4;          // 0..3
    const int jj  = q & 1;           // which of the wave's 2 outputs
    const int pp  = q >> 1;          // 0: gates i,f   1: gates g,o
    const int jg  = blockIdx.x * 16 + 2 * wv + jj;     // global h index
    const size_t R0 = (size_t)(2 * pp) * 1024 + jg;    // gate rows
    const size_t R1 = R0 + 1024;

    // ---- W_hh slice into registers (f32), fully unrolled static indexing ----
    f4_t Wa[16], Wb[16];
#pragma unroll
    for (int i = 0; i < 16; i++) {
        Wa[i] = *(const f4_t*)(Whh + R0 * 1024 + s * 64 + 4 * i);
        Wb[i] = *(const f4_t*)(Whh + R1 * 1024 + s * 64 + 4 * i);
    }

    float c = 0.f;   // cell state: lives in lanes l==0 / l==16 of each wave

    for (int t = 0; t < 2048; t++) {
        // prefetch xg rows before the spin so L3 latency hides under the wait
        float xg0 = 0.f, xg1 = 0.f;
        if (s == 0) {
            xg0 = xg[(size_t)t * 4096 + R0];
            xg1 = xg[(size_t)t * 4096 + R1];
        }
        asm volatile("" :: "v"(xg0), "v"(xg1));

        float* hb = &hl[t & 1][0];
        const int e = 2 * tid;
        float* dst = hb + ((e >> 6) * 68 + (e & 63));
        if (t == 0) {
            dst[0] = 0.f; dst[1] = 0.f;
        } else {
            const unsigned* src = hs + (size_t)(t - 1) * 1024 + e;
            u32x2 u = ld_coherent_x2(src);
            while (u.x == SENT || u.y == SENT) {
                __builtin_amdgcn_s_sleep(1);
                u = ld_coherent_x2(src);
            }
            dst[0] = __uint_as_float(u.x);
            dst[1] = __uint_as_float(u.y);
        }
        __syncthreads();   // the ONLY barrier per step (hl double-buffered)

        // dot: rows R0,R1 over k in [64s, 64s+64) — h reads shared by both rows
        const float* hp = hb + s * 68;
        f2_t a0 = f2_t{0.f, 0.f}, a1 = f2_t{0.f, 0.f};
        f2_t b0 = f2_t{0.f, 0.f}, b1 = f2_t{0.f, 0.f};
#pragma unroll
        for (int i = 0; i < 16; i++) {
            f4_t hv = *(const f4_t*)(hp + 4 * i);
            a0 = pkfma(lo2(Wa[i]), lo2(hv), a0);
            a1 = pkfma(hi2(Wa[i]), hi2(hv), a1);
            b0 = pkfma(lo2(Wb[i]), lo2(hv), b0);
            b1 = pkfma(hi2(Wb[i]), hi2(hv), b1);
        }
        float d0 = (a0.x + a0.y) + (a1.x + a1.y);
        float d1 = (b0.x + b0.y) + (b1.x + b1.y);
#pragma unroll
        for (int off = 8; off; off >>= 1) {
            d0 += __shfl_down(d0, off);
            d1 += __shfl_down(d1, off);
        }
        d0 += xg0;                       // 0 on non-s0 lanes
        d1 += xg1;
        // bring gates g,o (lanes q>=2) down to the i,f lanes (q<2)
        float e0 = __shfl_down(d0, 32);
        float e1 = __shfl_down(d1, 32);

        if (q < 2 && s == 0) {           // lanes 0 and 16: own output jg
            float gi = sigm(d0);
            float gf = sigm(d1);
            float gg = tanh_fast(e0);
            float go = sigm(e1);
            c = gf * c + gi * gg;
            float h = go * tanh_fast(c);
            __hip_atomic_store(hs + (size_t)t * 1024 + jg, __float_as_uint(h),
                               __ATOMIC_RELAXED, __HIP_MEMORY_SCOPE_AGENT);
        }
        // no trailing barrier: writes to this hl buffer recur at t+2, which is
        // ordered after this step's reads by the barrier at t+1.
    }
}

// ---------------- in-place log_softmax over rows of N ----------------
__global__ __launch_bounds__(256) void logsoftmax_rows(float* __restrict__ P, int N) {
    __shared__ float sm[4], sl[4], sfin;
    const int tid = threadIdx.x;
    float* p = P + (size_t)blockIdx.x * N;
    float m = -3.4e38f, l = 0.f;
    for (int i = tid; i < N; i += 256) {
        float x = p[i];
        float M = fmaxf(m, x);
        l = l * __expf(m - M) + __expf(x - M);
        m = M;
    }
    for (int off = 32; off; off >>= 1) {
        float m2 = __shfl_down(m, off);
        float l2 = __shfl_down(l, off);
        float M = fmaxf(m, m2);
        l = l * __expf(m - M) + l2 * __expf(m2 - M);
        m = M;
    }
    if ((tid & 63) == 0) { sm[tid >> 6] = m; sl[tid >> 6] = l; }
    __syncthreads();
    if (tid == 0) {
        m = sm[0]; l = sl[0];
        for (int w = 1; w < 4; w++) {
            float M = fmaxf(m, sm[w]);
            l = l * __expf(m - M) + sl[w] * __expf(sm[w] - M);
            m = M;
        }
        sfin = m + logf(l);
    }
    __syncthreads();
    float lse = sfin;
    for (int i = tid; i < N; i += 256) p[i] = p[i] - lse;
}

extern "C" void kernel_launch(void* const* d_in, const int* in_sizes, int n_in,
                              void* d_out, int out_size, void* d_ws, size_t ws_size,
                              hipStream_t stream) {
    const int*   sentence = (const int*)  d_in[0];
    const float* wte      = (const float*)d_in[1];
    const float* W_ih     = (const float*)d_in[2];
    const float* W_hh     = (const float*)d_in[3];
    const float* b_ih     = (const float*)d_in[4];
    const float* b_hh     = (const float*)d_in[5];
    const float* W_head   = (const float*)d_in[6];
    const float* b_head   = (const float*)d_in[7];
    float* out = (float*)d_out;

    char* ws = (char*)d_ws;
    float* xg  = (float*)ws;                          // 2048*4096*4 = 33,554,432
    float* emb = (float*)(ws + 33554432);             // 2048*1024*4 =  8,388,608
    float* hsf = (float*)(ws + 41943040);             // 2048*1024*4 =  8,388,608
    unsigned* hsu = (unsigned*)hsf;

    fill_sent<<<2048, 256, 0, stream>>>(hsu);
    gather_emb<<<2048, 256, 0, stream>>>(sentence, wte, emb);

    dim3 g1(2048 / 128, 4096 / 128);   // (16, 32)
    gemm_bt<<<g1, 256, 0, stream>>>(emb, W_ih, b_ih, b_hh, xg, 2048, 4096, 1024);

    lstm_scan<<<64, 512, 0, stream>>>(W_hh, xg, hsu);

    dim3 g2(2048 / 128, (50257 + 127) / 128);  // (16, 393)
    gemm_bt<<<g2, 256, 0, stream>>>(hsf, W_head, b_head, nullptr, out, 2048, 50257, 1024);

    logsoftmax_rows<<<2048, 256, 0, stream>>>(out, 50257);
}